// Round 7
// baseline (626.281 us; speedup 1.0000x reference)
//
#include <hip/hip_runtime.h>
#include <math.h>

#define NLAT 361
#define NLON 720
#define EPSF 1e-7f
#define T0F 8.72664625997164788e-3f   // 2*pi/720

typedef __attribute__((ext_vector_type(8))) short short8;
typedef __attribute__((ext_vector_type(4))) float f32x4;

// ---------------------------------------------------------------------------
// Kernel 1: real DFT over longitude (byte-identical since R4 — held constant;
// per-dispatch counters for it should finally appear next round).
// Output: GG[m][j][bc] = float4(Fp.re, Fp.im, Ft.re, Ft.im) * (2pi/720)*w[j]
// ---------------------------------------------------------------------------
__global__ __launch_bounds__(256) void dft_kernel(const float* __restrict__ pred,
                                                  const float* __restrict__ targ,
                                                  const float* __restrict__ wq,
                                                  float4* __restrict__ GG) {
  const int bc = blockIdx.y;
  const int j0 = blockIdx.x * 4;
  const int r  = threadIdx.x >> 6;   // wave id = row within block
  const int t  = threadIdx.x & 63;
  const int j  = j0 + r;

  __shared__ float4 EOa[4][180];   // even-m set
  __shared__ float4 EOb[4][180];   // odd-m set
  __shared__ float4 cR[4][2];

  if (j <= 360) {
    const float* fp = pred + ((size_t)bc * NLAT + j) * NLON;
    const float* ft = targ + ((size_t)bc * NLAT + j) * NLON;
    for (int n = 1 + t; n <= 179; n += 64) {
      float pa = fp[n], pb = fp[720 - n], pc = fp[360 - n], pd = fp[360 + n];
      float ta = ft[n], tb = ft[720 - n], tc = ft[360 - n], td = ft[360 + n];
      float eP = pa + pb, oP = pa - pb, e2P = pc + pd, o2P = pc - pd;
      float eT = ta + tb, oT = ta - tb, e2T = tc + td, o2T = tc - td;
      EOa[r][n] = make_float4(eP + e2P, oP - o2P, eT + e2T, oT - o2T);
      EOb[r][n] = make_float4(eP - e2P, oP + o2P, eT - e2T, oT + o2T);
    }
    if (t == 0) {
      cR[r][0] = make_float4(fp[0], fp[360], fp[180] + fp[540], fp[180] - fp[540]);
      cR[r][1] = make_float4(ft[0], ft[360], ft[180] + ft[540], ft[180] - ft[540]);
    }
  }
  __syncthreads();
  if (j > 360) return;

  const float4* eo = (t & 1) ? EOb[r] : EOa[r];

  float rc1[3], rs1[3], rc2[3], rs2[3], stc[3], sts[3];
#pragma unroll
  for (int s = 0; s < 3; ++s) {
    int m = t + 64 * s;
    sincosf(T0F * (float)m, &rs1[s], &rc1[s]);
    sincosf(T0F * (float)(2 * m), &sts[s], &stc[s]);
    rc2[s] = stc[s]; rs2[s] = sts[s];
  }

  float aCoP[3], aSoP[3], aCeP[3], aSeP[3];
  float aCoT[3], aSoT[3], aCeT[3], aSeT[3];
#pragma unroll
  for (int s = 0; s < 3; ++s) {
    aCoP[s] = aSoP[s] = aCeP[s] = aSeP[s] = 0.f;
    aCoT[s] = aSoT[s] = aCeT[s] = aSeT[s] = 0.f;
  }

  for (int k = 1; k <= 89; ++k) {
    float4 X1 = eo[2 * k - 1];
    float4 X2 = eo[2 * k];
#pragma unroll
    for (int s = 0; s < 3; ++s) {
      aCoP[s] = fmaf(X1.x, rc1[s], aCoP[s]);
      aSoP[s] = fmaf(X1.y, rs1[s], aSoP[s]);
      aCoT[s] = fmaf(X1.z, rc1[s], aCoT[s]);
      aSoT[s] = fmaf(X1.w, rs1[s], aSoT[s]);
      aCeP[s] = fmaf(X2.x, rc2[s], aCeP[s]);
      aSeP[s] = fmaf(X2.y, rs2[s], aSeP[s]);
      aCeT[s] = fmaf(X2.z, rc2[s], aCeT[s]);
      aSeT[s] = fmaf(X2.w, rs2[s], aSeT[s]);
      float nc1 = fmaf(rc1[s], stc[s], -(rs1[s] * sts[s]));
      float ns1 = fmaf(rs1[s], stc[s],  (rc1[s] * sts[s]));
      rc1[s] = nc1; rs1[s] = ns1;
      float nc2 = fmaf(rc2[s], stc[s], -(rs2[s] * sts[s]));
      float ns2 = fmaf(rs2[s], stc[s],  (rc2[s] * sts[s]));
      rc2[s] = nc2; rs2[s] = ns2;
    }
  }
  {
    float4 X1 = eo[179];
#pragma unroll
    for (int s = 0; s < 3; ++s) {
      aCoP[s] = fmaf(X1.x, rc1[s], aCoP[s]);
      aSoP[s] = fmaf(X1.y, rs1[s], aSoP[s]);
      aCoT[s] = fmaf(X1.z, rc1[s], aCoT[s]);
      aSoT[s] = fmaf(X1.w, rs1[s], aSoT[s]);
    }
  }

  const float sgn = (t & 1) ? -1.f : 1.f;
  const float4 cP = cR[r][0];
  const float4 cT = cR[r][1];
  const float sc = T0F * wq[j];
  const float BP = fmaf(sgn, cP.y, cP.x);
  const float BT = fmaf(sgn, cT.y, cT.x);

#pragma unroll
  for (int s = 0; s < 3; ++s) {
    const int m = t + 64 * s;
    if (m > 180) continue;
    const float s2 = (m & 2) ? -1.f : 1.f;
    const float cReP = (m & 1) ? 0.f : s2 * cP.z;
    const float cReT = (m & 1) ? 0.f : s2 * cT.z;
    const float cImP = (m & 1) ? s2 * cP.w : 0.f;
    const float cImT = (m & 1) ? s2 * cT.w : 0.f;
    {
      float ReP = BP + aCeP[s] + aCoP[s] + cReP;
      float ImP = -(aSeP[s] + aSoP[s] + cImP);
      float ReT = BT + aCeT[s] + aCoT[s] + cReT;
      float ImT = -(aSeT[s] + aSoT[s] + cImT);
      GG[((size_t)m * NLAT + j) * 16 + bc] =
          make_float4(ReP * sc, ImP * sc, ReT * sc, ImT * sc);
    }
    if (m >= 1 && m <= 179) {
      int m2 = 360 - m;
      float ReP = BP + aCeP[s] - aCoP[s] + cReP;
      float ImP = (aSeP[s] - aSoP[s]) + cImP;
      float ReT = BT + aCeT[s] - aCoT[s] + cReT;
      float ImT = (aSeT[s] - aSoT[s]) + cImT;
      GG[((size_t)m2 * NLAT + j) * 16 + bc] =
          make_float4(ReP * sc, ImP * sc, ReT * sc, ImT * sc);
    }
  }
}

// ---------------------------------------------------------------------------
// Kernel 2: Legendre contraction as MFMA GEMM (bf16 split-2) + fused
// triangular PSD/cross-spectrum epilogue.
// Per (m, parity): C[l_rows, n=64] = A[rows, K=181] x B[K=181, n] where
// A = stride-2 leg rows (parity-matched; each row fetched once device-wide),
// B = parity-folded spectral row U (folded from GG during staging).
// Split: X = Xh + Xl (bf16 truncation); keep AhBh + AhBl + AlBh (err ~5e-5).
// Block: 32 rows x 64 n x full K. 4 waves = 4 n-tiles; 2 m-tiles/wave.
// LDS: A 25.6 KB + B 51.2 KB (KPAD=200 -> 16B-aligned b128 frags, 2-way banks).
// Epilogue: C frags -> LDS R -> quadratics -> 4 atomics per (row,bc).
// ---------------------------------------------------------------------------
#define KPAD 200
#define KSTEPS 6
__global__ __launch_bounds__(256) void leg_kernel(const float* __restrict__ leg,
                                                  const float* __restrict__ GGf,
                                                  float* __restrict__ S) {
  const int m   = blockIdx.x >> 1;
  const int par = blockIdx.x & 1;
  const int lstart = m + ((m ^ par) & 1);        // first l >= m with l%2 == par
  if (lstart > 359) return;
  const int rows_total = ((359 - lstart) >> 1) + 1;
  const int r0 = 32 * blockIdx.y;
  if (r0 >= rows_total) return;
  const int nrows = (rows_total - r0 < 32) ? rows_total - r0 : 32;
  const int lbase = lstart + 2 * r0;

  // A: [hl*6400 + row*200 + k] shorts; B: 12800 + [hl*12800 + n*200 + k]
  __shared__ __align__(16) short sAB[38400];     // 76.8 KB
  short* Ab = sAB;
  short* Bb = sAB + 12800;

  const int tid = threadIdx.x;
  const int sel = (m + par) & 1;                 // (l+m) parity
  const float sgnU = sel ? -1.f : 1.f;

  // ---- stage B: fold GG[m] + bf16 hi/lo split ----
  {
    const float* gm = GGf + (size_t)m * (NLAT * 64);
    const int n  = tid >> 2;        // 0..63
    const int ko = tid & 3;
    for (int k = ko; k < KPAD; k += 4) {
      float u = 0.f;
      if (k < 180)       u = fmaf(sgnU, gm[(360 - k) * 64 + n], gm[k * 64 + n]);
      else if (k == 180) u = sel ? 0.f : gm[180 * 64 + n];
      unsigned hb = __float_as_uint(u) >> 16;
      float rr = u - __uint_as_float(hb << 16);
      unsigned lb = __float_as_uint(rr) >> 16;
      Bb[n * KPAD + k]         = (short)hb;
      Bb[12800 + n * KPAD + k] = (short)lb;
    }
  }
  // ---- stage A: leg rows + bf16 hi/lo split ----
  {
    const int row = tid >> 3;       // 0..31
    const int ko  = tid & 7;
    const bool ok = (row < nrows);
    const float* lr = ok ? leg + ((size_t)(lbase + 2 * row) * NLAT + m) * NLAT
                         : leg;
    for (int k = ko; k < KPAD; k += 8) {
      float v = (ok && k <= 180) ? lr[k] : 0.f;
      unsigned hb = __float_as_uint(v) >> 16;
      float rr = v - __uint_as_float(hb << 16);
      unsigned lb = __float_as_uint(rr) >> 16;
      Ab[row * KPAD + k]        = (short)hb;
      Ab[6400 + row * KPAD + k] = (short)lb;
    }
  }
  __syncthreads();

  // ---- MFMA main loop ----
  const int lane = tid & 63;
  const int w    = tid >> 6;        // n-tile (n = w*16 + col)
  const int col  = lane & 15;
  const int quad = lane >> 4;

  f32x4 acc0 = {0.f, 0.f, 0.f, 0.f};
  f32x4 acc1 = {0.f, 0.f, 0.f, 0.f};

  const short* Bh_p = Bb + (w * 16 + col) * KPAD + quad * 8;
  const short* Bl_p = Bh_p + 12800;
  const short* Ah_p = Ab + col * KPAD + quad * 8;
  const short* Al_p = Ah_p + 6400;

#pragma unroll
  for (int ks = 0; ks < KSTEPS; ++ks) {
    short8 bh  = *(const short8*)(Bh_p + ks * 32);
    short8 bl  = *(const short8*)(Bl_p + ks * 32);
    short8 ah0 = *(const short8*)(Ah_p + ks * 32);
    short8 al0 = *(const short8*)(Al_p + ks * 32);
    short8 ah1 = *(const short8*)(Ah_p + 16 * KPAD + ks * 32);
    short8 al1 = *(const short8*)(Al_p + 16 * KPAD + ks * 32);
    acc0 = __builtin_amdgcn_mfma_f32_16x16x32_bf16(ah0, bh, acc0, 0, 0, 0);
    acc0 = __builtin_amdgcn_mfma_f32_16x16x32_bf16(ah0, bl, acc0, 0, 0, 0);
    acc0 = __builtin_amdgcn_mfma_f32_16x16x32_bf16(al0, bh, acc0, 0, 0, 0);
    acc1 = __builtin_amdgcn_mfma_f32_16x16x32_bf16(ah1, bh, acc1, 0, 0, 0);
    acc1 = __builtin_amdgcn_mfma_f32_16x16x32_bf16(ah1, bl, acc1, 0, 0, 0);
    acc1 = __builtin_amdgcn_mfma_f32_16x16x32_bf16(al1, bh, acc1, 0, 0, 0);
  }

  // ---- epilogue: C frags -> LDS -> quadratics -> atomics ----
  __syncthreads();                  // staging tiles dead; reuse as R[32][68]
  float* R = (float*)sAB;
#pragma unroll
  for (int q = 0; q < 4; ++q) {
    R[(quad * 4 + q) * 68 + w * 16 + col]        = acc0[q];
    R[(16 + quad * 4 + q) * 68 + w * 16 + col]   = acc1[q];
  }
  __syncthreads();

  const int row = tid >> 4;         // 0..15
  const int bc  = tid & 15;
  const float ef = (m == 0) ? 1.f : 2.f;
#pragma unroll
  for (int h = 0; h < 2; ++h) {
    const int rr = row + 16 * h;
    if (rr < nrows) {
      float4 v = *(const float4*)&R[rr * 68 + bc * 4];
      float pr = v.x, pi = v.y, tr = v.z, ti = v.w;
      const int l = lbase + 2 * rr;
      float* sp = S + ((size_t)bc * 360 + l) * 4;
      atomicAdd(sp + 0, ef * (pr * pr + pi * pi));
      atomicAdd(sp + 1, ef * (tr * tr + ti * ti));
      atomicAdd(sp + 2, ef * (pr * tr + pi * ti));
      atomicAdd(sp + 3, ef * (pr * ti - pi * tr));
    }
  }
}

// ---------------------------------------------------------------------------
// Kernel 3: final loss epilogue + reduction. One block.
// ---------------------------------------------------------------------------
__global__ void loss_kernel(const float* __restrict__ S,
                            const float* __restrict__ wts,
                            float* __restrict__ out) {
  const int tid = threadIdx.x;
  float acc = 0.f;
  for (int i = tid; i < 16 * 360; i += 256) {
    int bc = i / 360;
    const float* sp = S + (size_t)i * 4;
    float pp = sp[0] + EPSF;
    float tp = sp[1] + EPSF;
    float sr = sp[2], si = sp[3];
    float mag   = sqrtf(sr * sr + si * si);
    float denom = sqrtf(pp * tp + EPSF);
    float coh   = mag / (denom + EPSF);
    coh = fminf(fmaxf(coh, 0.f), 1.f);
    float sqp = sqrtf(pp), sqt = sqrtf(tp);
    float amp = (sqp - sqt) * (sqp - sqt);
    float dec = 2.f * fmaxf(pp, tp) * (1.f - coh);
    acc += (amp + dec) * wts[bc & 7];
  }
  __shared__ float red[4];
#pragma unroll
  for (int off = 32; off > 0; off >>= 1) acc += __shfl_xor(acc, off, 64);
  if ((tid & 63) == 0) red[tid >> 6] = acc;
  __syncthreads();
  if (tid == 0) {
    float loss = (red[0] + red[1] + red[2] + red[3]) / (360.f * 16.f);
    out[0] = isnan(loss) ? 1e6f : loss;
  }
}

// ---------------------------------------------------------------------------
extern "C" void kernel_launch(void* const* d_in, const int* in_sizes, int n_in,
                              void* d_out, int out_size, void* d_ws, size_t ws_size,
                              hipStream_t stream) {
  const float* pred = (const float*)d_in[0];   // [2,8,361,720]
  const float* targ = (const float*)d_in[1];   // [2,8,361,720]
  const float* wts  = (const float*)d_in[2];   // [8]
  const float* leg  = (const float*)d_in[3];   // [361,361,361]
  const float* wq   = (const float*)d_in[4];   // [361]
  float* out = (float*)d_out;

  float4* GG = (float4*)d_ws;                            // [360][361][16] float4
  float*  S  = (float*)(GG + (size_t)360 * NLAT * 16);   // [16][360][4]

  hipMemsetAsync(S, 0, (size_t)16 * 360 * 4 * sizeof(float), stream);

  dft_kernel<<<dim3(91, 16), 256, 0, stream>>>(pred, targ, wq, GG);

  // x: 360 m * 2 parity classes; y: 32-row chunks (max 6); extras early-exit
  leg_kernel<<<dim3(720, 6), 256, 0, stream>>>(leg, (const float*)GG, S);

  loss_kernel<<<1, 256, 0, stream>>>(S, wts, out);
}